// Round 3
// baseline (61.787 us; speedup 1.0000x reference)
//
#include <hip/hip_runtime.h>

// Problem constants
constexpr int NROWS     = 32;
constexpr int HW        = 768 * 768;        // 589824 pixels per image
constexpr int CHUNKS    = 64;               // chunks per row in main pass
constexpr int CHUNK_PIX = HW / CHUNKS;      // 9216
constexpr int NB        = 4096;             // histogram buckets (float bits >> 19)
constexpr int THREADS   = 256;

// Workspace layout (bytes)
constexpr size_t OFF_ROWPART = 0;                                  // float [NROWS*CHUNKS] = 8 KB
constexpr size_t OFF_ROWC    = 8192;                               // double[NROWS]
constexpr size_t OFF_ROWTOT  = 8448;                               // double[NROWS]
constexpr size_t OFF_HIST64  = 16384;                              // ull   [NROWS*NB] = 1 MB
constexpr size_t WS_USED     = OFF_HIST64 + (size_t)NROWS * NB * 8;

// Zero the packed histogram: 1 MB = 65536 x 16 B.
__global__ __launch_bounds__(256) void zero_hist_kernel(ulonglong2* __restrict__ h)
{
    h[(size_t)blockIdx.x * 256 + threadIdx.x] = ulonglong2{0ull, 0ull};
}

__device__ __forceinline__ void px(float a0, float a1, unsigned t,
                                   float& lsum, unsigned* lh)
{
    constexpr float L2E = 1.4426950408889634f;
    float u = (a0 - a1) * L2E;                           // margin * log2(e)
    u = __uint_as_float(__float_as_uint(u) ^ (t << 31)); // sign flip if t==1
    // ce2 = ce/ln2 = max(-u,0) + log2(1 + 2^-|u|)   (>= 0, monotone in ce)
    const float e2  = exp2f(-fabsf(u));
    const float ce2 = fmaxf(-u, 0.f) + __log2f(1.f + e2);
    lsum += ce2;
    unsigned key = __float_as_uint(ce2) >> 19;           // monotone for ce2 >= 0
    if (key > NB - 1) key = NB - 1;
    atomicAdd(&lh[key], 1u | (t << 16));                 // one packed LDS atomic
}

// Pass 1: per (row, chunk) block — ce2 partial row-sum + packed histogram.
// LDS packed: low16 = all count, high16 = positives (block pixels = 9216 < 2^16).
// Global packed 64-bit: low32 = positives, high32 = all.
__global__ __launch_bounds__(THREADS) void ce_hist_kernel(
    const float* __restrict__ logits, const int* __restrict__ targets,
    float* __restrict__ rowpart, unsigned long long* __restrict__ hist)
{
    __shared__ unsigned lh[NB];
    __shared__ float    redf[THREADS / 64];

    const int blk   = blockIdx.x;
    const int row   = blk / CHUNKS;
    const int chunk = blk % CHUNKS;

    for (int b = threadIdx.x; b < NB; b += THREADS) lh[b] = 0u;
    __syncthreads();

    const float* x0 = logits + (size_t)row * 2 * HW + (size_t)chunk * CHUNK_PIX;
    const float* x1 = x0 + HW;
    const int*   tp = targets + (size_t)row * HW + (size_t)chunk * CHUNK_PIX;

    float lsum = 0.f;

    // 4 main iterations of 8 px/lane (2048 px/iter), fully unrolled so the
    // compiler hoists/overlaps the 24 global loads; then one 4 px/lane tail.
#pragma unroll
    for (int it = 0; it < 4; ++it) {
        const int p = it * (THREADS * 8) + threadIdx.x * 8;
        const float4 a0 = *(const float4*)(x0 + p);
        const float4 b0 = *(const float4*)(x0 + p + 4);
        const float4 a1 = *(const float4*)(x1 + p);
        const float4 b1 = *(const float4*)(x1 + p + 4);
        const int4   t0 = *(const int4*)(tp + p);
        const int4   t1 = *(const int4*)(tp + p + 4);
        const float* va0 = (const float*)&a0;
        const float* vb0 = (const float*)&b0;
        const float* va1 = (const float*)&a1;
        const float* vb1 = (const float*)&b1;
        const int*   tv0 = (const int*)&t0;
        const int*   tv1 = (const int*)&t1;
#pragma unroll
        for (int j = 0; j < 4; ++j) px(va0[j], va1[j], (unsigned)tv0[j], lsum, lh);
#pragma unroll
        for (int j = 0; j < 4; ++j) px(vb0[j], vb1[j], (unsigned)tv1[j], lsum, lh);
    }
    {   // tail: 1024 px = 256 lanes x 4
        const int p = 4 * (THREADS * 8) + threadIdx.x * 4;
        const float4 a0 = *(const float4*)(x0 + p);
        const float4 a1 = *(const float4*)(x1 + p);
        const int4   t0 = *(const int4*)(tp + p);
        const float* va0 = (const float*)&a0;
        const float* va1 = (const float*)&a1;
        const int*   tv0 = (const int*)&t0;
#pragma unroll
        for (int j = 0; j < 4; ++j) px(va0[j], va1[j], (unsigned)tv0[j], lsum, lh);
    }

    // wave-reduce the ce2 sum
    for (int o = 32; o > 0; o >>= 1) lsum += __shfl_down(lsum, o);
    const int wid  = threadIdx.x >> 6;
    const int lane = threadIdx.x & 63;
    if (lane == 0) redf[wid] = lsum;
    __syncthreads();   // also orders all LDS histogram atomics before flush

    if (threadIdx.x == 0) {
        float s = 0.f;
        for (int w = 0; w < THREADS / 64; ++w) s += redf[w];
        rowpart[row * CHUNKS + chunk] = s;            // deterministic partial
    }

    // flush: one 64-bit global atomic per nonzero bucket
    for (int b = threadIdx.x; b < NB; b += THREADS) {
        const unsigned v = lh[b];
        if (v) {
            const unsigned long long add =
                ((unsigned long long)(v & 0xFFFFu) << 32) | (v >> 16);
            atomicAdd(&hist[(size_t)row * NB + b], add);
        }
    }
}

// Pass 2: one block per row — positives count, top-k threshold bucket,
// positives above it, proportional split of the threshold bucket.
__global__ __launch_bounds__(256) void select_kernel(
    const unsigned long long* __restrict__ hist,
    const float* __restrict__ rowpart,
    double* __restrict__ rowC, double* __restrict__ rowtot)
{
    __shared__ unsigned lh[NB];
    __shared__ unsigned lph[NB];
    __shared__ unsigned segsum[256];
    __shared__ unsigned segpsum[256];
    __shared__ unsigned segsuf[256];
    __shared__ int      s_tb;
    __shared__ unsigned s_cgt;
    __shared__ unsigned s_posgt;
    __shared__ unsigned s_pos;

    const int row = blockIdx.x;
    const int tid = threadIdx.x;

    for (int b = tid; b < NB; b += 256) {
        const unsigned long long v = hist[(size_t)row * NB + b];
        lh[b]  = (unsigned)(v >> 32);       // all
        lph[b] = (unsigned)(v & 0xFFFFFFFFu); // positives
    }
    __syncthreads();

    // Each thread owns 16 buckets; thread 0 owns the TOP 16 (descending segments).
    const int base = NB - 16 * (tid + 1);
    unsigned ssum = 0u, psum = 0u;
#pragma unroll
    for (int j = 0; j < 16; ++j) { ssum += lh[base + j]; psum += lph[base + j]; }
    segsum[tid]  = ssum;
    segpsum[tid] = psum;
    __syncthreads();

    if (tid == 0) {
        unsigned c = 0u, pc = 0u;
        for (int t = 0; t < 256; ++t) { segsuf[t] = c; c += segsum[t]; pc += segpsum[t]; }
        s_pos   = pc;
        s_tb    = -1;
        s_cgt   = 0u;
        s_posgt = 0u;
    }
    __syncthreads();

    const unsigned pos = s_pos;
    const unsigned k   = min(pos, (unsigned)HW - pos);

    if (k > 0) {
        const unsigned above = segsuf[tid];
        if (above < k && above + ssum >= k) {      // exactly one thread matches
            unsigned cum = above;
            for (int b = base + 15; b >= base; --b) {
                const unsigned nv = cum + lh[b];
                if (nv >= k) { s_tb = b; s_cgt = cum; break; }
                cum = nv;
            }
        }
    }
    __syncthreads();

    const int tb = s_tb;
    unsigned mypos = 0u;
    if (tb >= 0) {
#pragma unroll
        for (int j = 0; j < 16; ++j) {
            const int b = base + j;
            if (b > tb) mypos += lph[b];
        }
    }
    for (int o = 32; o > 0; o >>= 1) mypos += __shfl_down(mypos, o);
    if ((tid & 63) == 0) atomicAdd(&s_posgt, mypos);
    __syncthreads();

    if (tid == 0) {
        double Cr = 0.0;
        if (k > 0 && tb >= 0) {
            const unsigned rneed = k - s_cgt;          // 1..lh[tb]
            const unsigned hb = lh[tb], phb = lph[tb];
            const double P = (double)s_posgt +
                             (hb ? (double)rneed * (double)phb / (double)hb : 0.0);
            Cr = 2.0 * (double)k - P;                  // |A ∪ B|
        }
        rowC[row] = Cr;
        double s = 0.0;
        for (int c = 0; c < CHUNKS; ++c) s += (double)rowpart[row * CHUNKS + c];
        rowtot[row] = s;                               // ce2 domain (× ln2 at the end)
    }
}

// Pass 3: final scalar.  out = ((nL - C)*r0 + C*r1) / nL, r in nat-log units.
__global__ void final_kernel(const double* __restrict__ rowC,
                             const double* __restrict__ rowtot,
                             float* __restrict__ out)
{
    constexpr double LN2 = 0.6931471805599453;
    double C = 0.0;
    for (int r = 0; r < NROWS; ++r) C += rowC[r];
    const double nL = (double)NROWS * (double)HW;
    const double r0 = rowtot[0] / (double)HW * LN2;
    const double r1 = rowtot[1] / (double)HW * LN2;
    out[0] = (float)(((nL - C) * r0 + C * r1) / nL);
}

extern "C" void kernel_launch(void* const* d_in, const int* in_sizes, int n_in,
                              void* d_out, int out_size, void* d_ws, size_t ws_size,
                              hipStream_t stream) {
    const float* logits  = (const float*)d_in[0];
    const int*   targets = (const int*)d_in[1];
    float*       out     = (float*)d_out;
    char*        ws      = (char*)d_ws;

    zero_hist_kernel<<<NROWS * NB * 8 / (256 * 16), 256, 0, stream>>>(
        (ulonglong2*)(ws + OFF_HIST64));

    ce_hist_kernel<<<NROWS * CHUNKS, THREADS, 0, stream>>>(
        logits, targets,
        (float*)(ws + OFF_ROWPART),
        (unsigned long long*)(ws + OFF_HIST64));

    select_kernel<<<NROWS, 256, 0, stream>>>(
        (const unsigned long long*)(ws + OFF_HIST64),
        (const float*)(ws + OFF_ROWPART),
        (double*)(ws + OFF_ROWC), (double*)(ws + OFF_ROWTOT));

    final_kernel<<<1, 1, 0, stream>>>(
        (const double*)(ws + OFF_ROWC), (const double*)(ws + OFF_ROWTOT), out);
}